// Round 1
// baseline (655.043 us; speedup 1.0000x reference)
//
#include <hip/hip_runtime.h>
#include <math.h>

#define N_TOK 32768
#define DIM 512
#define NE 8
#define NF 2048
#define CCAP 4096

typedef __attribute__((ext_vector_type(4))) float floatx4;
typedef __attribute__((ext_vector_type(8))) short shortx8;
typedef __attribute__((ext_vector_type(4))) short shortx4;

__device__ __forceinline__ short f2bf(float f) {
  union { float f; unsigned u; } v; v.f = f;
  unsigned r = v.u + 0x7FFFu + ((v.u >> 16) & 1u);
  return (short)(r >> 16);
}

__device__ __forceinline__ unsigned f2key(float f) {
  union { float f; unsigned u; } v; v.f = f;
  return (v.u & 0x80000000u) ? ~v.u : (v.u | 0x80000000u);
}

__device__ __forceinline__ void gll16(const void* g, void* l) {
  __builtin_amdgcn_global_load_lds(
      (const __attribute__((address_space(1))) void*)g,
      (__attribute__((address_space(3))) void*)l, 16, 0, 0);
}

// ---------------- x fp32 -> bf16 ----------------
__global__ void k_convert_x(const float* __restrict__ x, short* __restrict__ xb) {
  const int total = N_TOK * DIM / 4;
  for (int i = blockIdx.x * blockDim.x + threadIdx.x; i < total;
       i += gridDim.x * blockDim.x) {
    floatx4 v = *(const floatx4*)(x + (size_t)i * 4);
    shortx4 o;
    o.x = f2bf(v.x); o.y = f2bf(v.y); o.z = f2bf(v.z); o.w = f2bf(v.w);
    *(shortx4*)(xb + (size_t)i * 4) = o;
  }
}

// ---------------- per-expert transpose fp32 [E][R][C] -> bf16 [E][C][R] ----------------
__global__ void k_transpose(const float* __restrict__ in, short* __restrict__ out,
                            int R, int Cc) {
  __shared__ float tile[32][33];
  const int e = blockIdx.z;
  const size_t base = (size_t)e * R * Cc;
  const int c0 = blockIdx.x * 32, r0 = blockIdx.y * 32;
  const int tx = threadIdx.x, ty = threadIdx.y;
#pragma unroll
  for (int i = 0; i < 4; i++)
    tile[ty + i * 8][tx] = in[base + (size_t)(r0 + ty + i * 8) * Cc + c0 + tx];
  __syncthreads();
#pragma unroll
  for (int i = 0; i < 4; i++)
    out[base + (size_t)(c0 + ty + i * 8) * R + r0 + tx] = f2bf(tile[tx][ty + i * 8]);
}

// ---------------- router logits: logitsT[e][n] = x[n,:].Wr[:,e] (fp64 accum) ----------------
__global__ void k_logits(const float* __restrict__ x, const float* __restrict__ Wr,
                         float* __restrict__ logitsT) {
  const int lane = threadIdx.x & 63;
  const int wave = (int)((blockIdx.x * blockDim.x + threadIdx.x) >> 6);
  const int nw = (int)((gridDim.x * blockDim.x) >> 6);
  float wr[64];  // Wr rows lane*8..lane*8+7, all 8 experts
#pragma unroll
  for (int i = 0; i < 16; i++)
    *(floatx4*)&wr[i * 4] = *(const floatx4*)&Wr[lane * 64 + i * 4];
  for (int n = wave; n < N_TOK; n += nw) {
    const float* xr = x + (size_t)n * DIM + lane * 8;
    floatx4 x0 = *(const floatx4*)xr;
    floatx4 x1 = *(const floatx4*)(xr + 4);
    float xs[8] = {x0.x, x0.y, x0.z, x0.w, x1.x, x1.y, x1.z, x1.w};
    double acc[8];
#pragma unroll
    for (int e2 = 0; e2 < 8; e2++) acc[e2] = 0.0;
#pragma unroll
    for (int j = 0; j < 8; j++) {
      double xv = (double)xs[j];
#pragma unroll
      for (int e2 = 0; e2 < 8; e2++) acc[e2] += xv * (double)wr[j * 8 + e2];
    }
#pragma unroll
    for (int e2 = 0; e2 < 8; e2++) {
#pragma unroll
      for (int off2 = 32; off2 > 0; off2 >>= 1)
        acc[e2] += __shfl_xor(acc[e2], off2);
    }
    double rv = acc[0];
#pragma unroll
    for (int e2 = 1; e2 < 8; e2++)
      if (lane == e2) rv = acc[e2];
    if (lane < 8) logitsT[(size_t)lane * N_TOK + n] = (float)rv;
  }
}

// ---------------- exact top-C threshold via 3-level radix select ----------------
__device__ void radix_find(unsigned* hist, unsigned* sA, unsigned* sB, int nbins,
                           unsigned target, unsigned* out_bin, unsigned* out_rem) {
  const int t = threadIdx.x, bd = blockDim.x;
  for (int i = t; i < nbins; i += bd) sA[i] = hist[i];
  __syncthreads();
  unsigned* src = sA;
  unsigned* dst = sB;
  for (int d = 1; d < nbins; d <<= 1) {
    for (int i = t; i < nbins; i += bd)
      dst[i] = src[i] + ((i + d < nbins) ? src[i + d] : 0u);
    __syncthreads();
    unsigned* tmp = src; src = dst; dst = tmp;
  }
  // src[i] = sum_{j>=i} hist[j]
  for (int i = t; i < nbins; i += bd) {
    unsigned gt = (i + 1 < nbins) ? src[i + 1] : 0u;
    if (gt < target && src[i] >= target) { *out_bin = (unsigned)i; *out_rem = target - gt; }
  }
  __syncthreads();
}

__global__ __launch_bounds__(1024) void k_select(const float* __restrict__ logitsT,
                                                 int* __restrict__ sel_idx,
                                                 float* __restrict__ sel_val) {
  __shared__ unsigned hist[2048], sA[2048], sB[2048];
  __shared__ float red[16];
  __shared__ float s_stat[2];  // max, 1/sumexp
  __shared__ unsigned s_bin, s_rem;
  __shared__ unsigned s_cnt[2];
  const int e = blockIdx.x;
  const int t = threadIdx.x;
  const int bd = blockDim.x;
  const float* lg = logitsT + (size_t)e * N_TOK;

  // max
  float m = -3.4e38f;
  for (int n = t; n < N_TOK; n += bd) m = fmaxf(m, lg[n]);
#pragma unroll
  for (int o = 32; o > 0; o >>= 1) m = fmaxf(m, __shfl_xor(m, o));
  if ((t & 63) == 0) red[t >> 6] = m;
  __syncthreads();
  if (t < 16) {
    float v = red[t];
#pragma unroll
    for (int o = 8; o > 0; o >>= 1) v = fmaxf(v, __shfl_xor(v, o));
    if (t == 0) s_stat[0] = v;
  }
  __syncthreads();
  m = s_stat[0];
  // sum exp
  float s = 0.f;
  for (int n = t; n < N_TOK; n += bd) s += expf(lg[n] - m);
#pragma unroll
  for (int o = 32; o > 0; o >>= 1) s += __shfl_xor(s, o);
  if ((t & 63) == 0) red[t >> 6] = s;
  __syncthreads();
  if (t < 16) {
    float v = red[t];
#pragma unroll
    for (int o = 8; o > 0; o >>= 1) v += __shfl_xor(v, o);
    if (t == 0) s_stat[1] = 1.0f / v;
  }
  // level 1: bits [31:21]
  for (int i = t; i < 2048; i += bd) hist[i] = 0;
  __syncthreads();
  for (int n = t; n < N_TOK; n += bd) atomicAdd(&hist[f2key(lg[n]) >> 21], 1u);
  __syncthreads();
  radix_find(hist, sA, sB, 2048, CCAP, &s_bin, &s_rem);
  const unsigned b1v = s_bin, t2 = s_rem;
  // level 2: bits [20:10]
  for (int i = t; i < 2048; i += bd) hist[i] = 0;
  __syncthreads();
  for (int n = t; n < N_TOK; n += bd) {
    unsigned k = f2key(lg[n]);
    if ((k >> 21) == b1v) atomicAdd(&hist[(k >> 10) & 0x7FFu], 1u);
  }
  __syncthreads();
  radix_find(hist, sA, sB, 2048, t2, &s_bin, &s_rem);
  const unsigned b2v = s_bin, t3 = s_rem;
  // level 3: bits [9:0]
  for (int i = t; i < 1024; i += bd) hist[i] = 0;
  __syncthreads();
  const unsigned pre22 = (b1v << 11) | b2v;
  for (int n = t; n < N_TOK; n += bd) {
    unsigned k = f2key(lg[n]);
    if ((k >> 10) == pre22) atomicAdd(&hist[k & 0x3FFu], 1u);
  }
  __syncthreads();
  radix_find(hist, sA, sB, 1024, t3, &s_bin, &s_rem);
  const unsigned b3v = s_bin, rr = s_rem;
  const unsigned T = (b1v << 21) | (b2v << 10) | b3v;
  if (t == 0) { s_cnt[0] = 0; s_cnt[1] = 0; }
  __syncthreads();
  const float inv = s_stat[1];
  for (int n = t; n < N_TOK; n += bd) {
    float lv = lg[n];
    unsigned k = f2key(lv);
    int pos = -1;
    if (k > T) {
      pos = (int)atomicAdd(&s_cnt[0], 1u);
    } else if (k == T) {
      unsigned q = atomicAdd(&s_cnt[1], 1u);
      if (q < rr) pos = (int)(CCAP - rr + q);
    }
    if (pos >= 0) {
      sel_idx[e * CCAP + pos] = n;
      sel_val[e * CCAP + pos] = expf(lv - m) * inv;
    }
  }
}

// ---------------- GEMM1: H = gelu(gather(x)[C,512] @ W1 + b1), bf16 out ----------------
__global__ __launch_bounds__(256) void k_gemm1(
    const short* __restrict__ xb, const short* __restrict__ w1t,
    const float* __restrict__ b1, const int* __restrict__ sel_idx,
    short* __restrict__ H, int e0) {
  __shared__ short ldsA[128 * 32];
  __shared__ short ldsB[128 * 32];
  const int zi = blockIdx.z;
  const int e = e0 + zi;
  const int c0 = blockIdx.y * 128;
  const int f0 = blockIdx.x * 128;
  const int t = threadIdx.x;
  const int lane = t & 63;
  const int w = t >> 6;
  const int wm = w & 1, wn = w >> 1;

  const int rA = t >> 2;       // 0..63
  const int kp = (t & 3) * 8;  // bf16 elements within 32-k step
  const int* selp = sel_idx + e * CCAP + c0;
  const short* gA0 = xb + (size_t)selp[rA] * DIM + kp;
  const short* gA1 = xb + (size_t)selp[64 + rA] * DIM + kp;
  const short* gB0 = w1t + (size_t)(e * NF + f0 + rA) * DIM + kp;
  const short* gB1 = gB0 + (size_t)64 * DIM;
  short* lA = ldsA + w * 512;
  short* lB = ldsB + w * 512;

  floatx4 acc[4][4];
#pragma unroll
  for (int i = 0; i < 4; i++)
#pragma unroll
    for (int j = 0; j < 4; j++) acc[i][j] = (floatx4){0.f, 0.f, 0.f, 0.f};

  const int arow = wm * 64 + (lane & 15);
  const int brow = wn * 64 + (lane & 15);
  const int koff = (lane >> 4) * 8;

  for (int kk = 0; kk < DIM / 32; ++kk) {
    __syncthreads();
    gll16(gA0, lA);
    gll16(gA1, lA + 2048);
    gll16(gB0, lB);
    gll16(gB1, lB + 2048);
    gA0 += 32; gA1 += 32; gB0 += 32; gB1 += 32;
    __syncthreads();
    shortx8 af[4], bf[4];
#pragma unroll
    for (int i = 0; i < 4; i++)
      af[i] = *(const shortx8*)&ldsA[(arow + i * 16) * 32 + koff];
#pragma unroll
    for (int j = 0; j < 4; j++)
      bf[j] = *(const shortx8*)&ldsB[(brow + j * 16) * 32 + koff];
#pragma unroll
    for (int i = 0; i < 4; i++)
#pragma unroll
      for (int j = 0; j < 4; j++)
        acc[i][j] = __builtin_amdgcn_mfma_f32_16x16x32_bf16(af[i], bf[j], acc[i][j], 0, 0, 0);
  }

  const int colb = wn * 64 + (lane & 15);
  const int rowb = wm * 64 + ((lane >> 4) << 2);
  const float* b1p = b1 + e * NF + f0;
  short* Hp = H + (size_t)zi * CCAP * NF;
#pragma unroll
  for (int j = 0; j < 4; j++) {
    float bv = b1p[colb + j * 16];
#pragma unroll
    for (int i = 0; i < 4; i++) {
#pragma unroll
      for (int r = 0; r < 4; r++) {
        float h = acc[i][j][r] + bv;
        float gl = 0.5f * h * (1.0f + erff(h * 0.7071067811865475f));
        Hp[(size_t)(c0 + rowb + i * 16 + r) * NF + f0 + colb + j * 16] = f2bf(gl);
      }
    }
  }
}

// ---------------- GEMM2: out[tok] += val * (H @ W2 + b2) ----------------
__global__ __launch_bounds__(256) void k_gemm2(
    const short* __restrict__ H, const short* __restrict__ w2t,
    const float* __restrict__ b2, const int* __restrict__ sel_idx,
    const float* __restrict__ sel_val, float* __restrict__ out, int e0) {
  __shared__ short ldsA[128 * 32];
  __shared__ short ldsB[128 * 32];
  __shared__ int tokL[128];
  __shared__ float valL[128];
  const int zi = blockIdx.z;
  const int e = e0 + zi;
  const int c0 = blockIdx.y * 128;
  const int d0 = blockIdx.x * 128;
  const int t = threadIdx.x;
  const int lane = t & 63;
  const int w = t >> 6;
  const int wm = w & 1, wn = w >> 1;
  if (t < 128) {
    tokL[t] = sel_idx[e * CCAP + c0 + t];
    valL[t] = sel_val[e * CCAP + c0 + t];
  }

  const int rA = t >> 2;
  const int kp = (t & 3) * 8;
  const short* gA0 = H + (size_t)(zi * CCAP + c0 + rA) * NF + kp;
  const short* gA1 = gA0 + (size_t)64 * NF;
  const short* gB0 = w2t + (size_t)(e * DIM + d0 + rA) * NF + kp;
  const short* gB1 = gB0 + (size_t)64 * NF;
  short* lA = ldsA + w * 512;
  short* lB = ldsB + w * 512;

  floatx4 acc[4][4];
#pragma unroll
  for (int i = 0; i < 4; i++)
#pragma unroll
    for (int j = 0; j < 4; j++) acc[i][j] = (floatx4){0.f, 0.f, 0.f, 0.f};

  const int arow = wm * 64 + (lane & 15);
  const int brow = wn * 64 + (lane & 15);
  const int koff = (lane >> 4) * 8;

  for (int kk = 0; kk < NF / 32; ++kk) {
    __syncthreads();
    gll16(gA0, lA);
    gll16(gA1, lA + 2048);
    gll16(gB0, lB);
    gll16(gB1, lB + 2048);
    gA0 += 32; gA1 += 32; gB0 += 32; gB1 += 32;
    __syncthreads();
    shortx8 af[4], bf[4];
#pragma unroll
    for (int i = 0; i < 4; i++)
      af[i] = *(const shortx8*)&ldsA[(arow + i * 16) * 32 + koff];
#pragma unroll
    for (int j = 0; j < 4; j++)
      bf[j] = *(const shortx8*)&ldsB[(brow + j * 16) * 32 + koff];
#pragma unroll
    for (int i = 0; i < 4; i++)
#pragma unroll
      for (int j = 0; j < 4; j++)
        acc[i][j] = __builtin_amdgcn_mfma_f32_16x16x32_bf16(af[i], bf[j], acc[i][j], 0, 0, 0);
  }

  const int colb = wn * 64 + (lane & 15);
  const int rowb = wm * 64 + ((lane >> 4) << 2);
  const float* b2p = b2 + e * DIM + d0;
#pragma unroll
  for (int j = 0; j < 4; j++) {
    float bv = b2p[colb + j * 16];
#pragma unroll
    for (int i = 0; i < 4; i++) {
#pragma unroll
      for (int r = 0; r < 4; r++) {
        int row = rowb + i * 16 + r;
        float o = acc[i][j][r] + bv;
        atomicAdd(&out[(size_t)tokL[row] * DIM + d0 + colb + j * 16], valL[row] * o);
      }
    }
  }
}

extern "C" void kernel_launch(void* const* d_in, const int* in_sizes, int n_in,
                              void* d_out, int out_size, void* d_ws, size_t ws_size,
                              hipStream_t stream) {
  const float* x = (const float*)d_in[0];
  const float* Wr = (const float*)d_in[1];
  const float* W1 = (const float*)d_in[2];
  const float* b1 = (const float*)d_in[3];
  const float* W2 = (const float*)d_in[4];
  const float* b2 = (const float*)d_in[5];
  float* out = (float*)d_out;

  char* p = (char*)d_ws;
  size_t off = 0;
  auto carve = [&](size_t bytes) {
    void* r = p + off;
    off = (off + bytes + 255) & ~(size_t)255;
    return r;
  };
  short* xb = (short*)carve((size_t)N_TOK * DIM * 2);
  short* w1t = (short*)carve((size_t)NE * NF * DIM * 2);
  short* w2t = (short*)carve((size_t)NE * DIM * NF * 2);
  float* logitsT = (float*)carve((size_t)NE * N_TOK * 4);
  int* selidx = (int*)carve((size_t)NE * CCAP * 4);
  float* selval = (float*)carve((size_t)NE * CCAP * 4);
  const size_t hbytes = (size_t)CCAP * NF * 2;
  int g = 1;
  if (off + 8 * hbytes <= ws_size) g = 8;
  else if (off + 4 * hbytes <= ws_size) g = 4;
  else if (off + 2 * hbytes <= ws_size) g = 2;
  short* Hbuf = (short*)carve((size_t)g * hbytes);

  hipMemsetAsync(d_out, 0, (size_t)out_size * 4, stream);
  k_convert_x<<<2048, 256, 0, stream>>>(x, xb);
  k_transpose<<<dim3(NF / 32, DIM / 32, NE), dim3(32, 8), 0, stream>>>(W1, w1t, DIM, NF);
  k_transpose<<<dim3(DIM / 32, NF / 32, NE), dim3(32, 8), 0, stream>>>(W2, w2t, NF, DIM);
  k_logits<<<2048, 256, 0, stream>>>(x, Wr, logitsT);
  k_select<<<NE, 1024, 0, stream>>>(logitsT, selidx, selval);
  for (int e0 = 0; e0 < NE; e0 += g) {
    k_gemm1<<<dim3(NF / 128, CCAP / 128, g), 256, 0, stream>>>(xb, w1t, b1, selidx, Hbuf, e0);
    k_gemm2<<<dim3(DIM / 128, CCAP / 128, g), 256, 0, stream>>>(Hbuf, w2t, b2, selidx, selval, out, e0);
  }
}

// Round 2
// 627.592 us; speedup vs baseline: 1.0437x; 1.0437x over previous
//
#include <hip/hip_runtime.h>
#include <math.h>

#define N_TOK 32768
#define DIM 512
#define NE 8
#define NF 2048
#define CCAP 4096

typedef __attribute__((ext_vector_type(4))) float floatx4;
typedef __attribute__((ext_vector_type(8))) short shortx8;
typedef __attribute__((ext_vector_type(4))) short shortx4;

__device__ __forceinline__ short f2bf(float f) {
  union { float f; unsigned u; } v; v.f = f;
  unsigned r = v.u + 0x7FFFu + ((v.u >> 16) & 1u);
  return (short)(r >> 16);
}

__device__ __forceinline__ unsigned f2key(float f) {
  union { float f; unsigned u; } v; v.f = f;
  return (v.u & 0x80000000u) ? ~v.u : (v.u | 0x80000000u);
}

__device__ __forceinline__ void gll16(const void* g, void* l) {
  __builtin_amdgcn_global_load_lds(
      (const __attribute__((address_space(1))) void*)g,
      (__attribute__((address_space(3))) void*)l, 16, 0, 0);
}

// ---------------- per-expert transpose fp32 [E][R][C] -> bf16 [E][C][R] ----------------
__global__ void k_transpose(const float* __restrict__ in, short* __restrict__ out,
                            int R, int Cc) {
  __shared__ float tile[32][33];
  const int e = blockIdx.z;
  const size_t base = (size_t)e * R * Cc;
  const int c0 = blockIdx.x * 32, r0 = blockIdx.y * 32;
  const int tx = threadIdx.x, ty = threadIdx.y;
#pragma unroll
  for (int i = 0; i < 4; i++)
    tile[ty + i * 8][tx] = in[base + (size_t)(r0 + ty + i * 8) * Cc + c0 + tx];
  __syncthreads();
#pragma unroll
  for (int i = 0; i < 4; i++)
    out[base + (size_t)(c0 + ty + i * 8) * R + r0 + tx] = f2bf(tile[tx][ty + i * 8]);
}

// ---------------- router logits: logitsT[e][n] = x[n,:].Wr[:,e] (fp64 accum) ----------------
__global__ void k_logits(const float* __restrict__ x, const float* __restrict__ Wr,
                         float* __restrict__ logitsT) {
  const int lane = threadIdx.x & 63;
  const int wave = (int)((blockIdx.x * blockDim.x + threadIdx.x) >> 6);
  const int nw = (int)((gridDim.x * blockDim.x) >> 6);
  float wr[64];  // Wr rows lane*8..lane*8+7, all 8 experts
#pragma unroll
  for (int i = 0; i < 16; i++)
    *(floatx4*)&wr[i * 4] = *(const floatx4*)&Wr[lane * 64 + i * 4];
  for (int n = wave; n < N_TOK; n += nw) {
    const float* xr = x + (size_t)n * DIM + lane * 8;
    floatx4 x0 = *(const floatx4*)xr;
    floatx4 x1 = *(const floatx4*)(xr + 4);
    float xs[8] = {x0.x, x0.y, x0.z, x0.w, x1.x, x1.y, x1.z, x1.w};
    double acc[8];
#pragma unroll
    for (int e2 = 0; e2 < 8; e2++) acc[e2] = 0.0;
#pragma unroll
    for (int j = 0; j < 8; j++) {
      double xv = (double)xs[j];
#pragma unroll
      for (int e2 = 0; e2 < 8; e2++) acc[e2] += xv * (double)wr[j * 8 + e2];
    }
#pragma unroll
    for (int e2 = 0; e2 < 8; e2++) {
#pragma unroll
      for (int off2 = 32; off2 > 0; off2 >>= 1)
        acc[e2] += __shfl_xor(acc[e2], off2);
    }
    double rv = acc[0];
#pragma unroll
    for (int e2 = 1; e2 < 8; e2++)
      if (lane == e2) rv = acc[e2];
    if (lane < 8) logitsT[(size_t)lane * N_TOK + n] = (float)rv;
  }
}

// ---------------- exact top-C via register-resident key bisection ----------------
__global__ __launch_bounds__(1024) void k_select(const float* __restrict__ logitsT,
                                                 int* __restrict__ sel_idx,
                                                 float* __restrict__ sel_val) {
  __shared__ float redf[16];
  __shared__ unsigned redu[16];
  __shared__ float s_max, s_inv;
  __shared__ unsigned s_tot;
  __shared__ unsigned s_cnt[2];
  const int e = blockIdx.x, t = threadIdx.x;
  const int wid = t >> 6, lane = t & 63;
  const float* lg = logitsT + (size_t)e * N_TOK;
  float lv[32];
  unsigned kv[32];
#pragma unroll
  for (int i = 0; i < 32; i++) lv[i] = lg[i * 1024 + t];
#pragma unroll
  for (int i = 0; i < 32; i++) kv[i] = f2key(lv[i]);
  // block max
  float m = lv[0];
#pragma unroll
  for (int i = 1; i < 32; i++) m = fmaxf(m, lv[i]);
#pragma unroll
  for (int o = 32; o > 0; o >>= 1) m = fmaxf(m, __shfl_xor(m, o));
  if (lane == 0) redf[wid] = m;
  __syncthreads();
  if (t == 0) {
    float v = redf[0];
    for (int i = 1; i < 16; i++) v = fmaxf(v, redf[i]);
    s_max = v;
  }
  __syncthreads();
  m = s_max;
  // block sum(exp)
  float s = 0.f;
#pragma unroll
  for (int i = 0; i < 32; i++) s += expf(lv[i] - m);
#pragma unroll
  for (int o = 32; o > 0; o >>= 1) s += __shfl_xor(s, o);
  if (lane == 0) redf[wid] = s;
  __syncthreads();
  if (t == 0) {
    float v = 0.f;
    for (int i = 0; i < 16; i++) v += redf[i];
    s_inv = 1.0f / v;
  }
  // bisection: T = C-th largest key
  unsigned T = 0;
  for (int b = 31; b >= 0; --b) {
    unsigned cand = T | (1u << b);
    unsigned c = 0;
#pragma unroll
    for (int i = 0; i < 32; i++) c += (kv[i] >= cand) ? 1u : 0u;
#pragma unroll
    for (int o = 32; o > 0; o >>= 1) c += __shfl_xor(c, o);
    if (lane == 0) redu[wid] = c;
    __syncthreads();
    if (t == 0) {
      unsigned v = 0;
      for (int i = 0; i < 16; i++) v += redu[i];
      s_tot = v;
    }
    __syncthreads();
    if (s_tot >= CCAP) T = cand;
  }
  // count strictly greater than T
  {
    unsigned c = 0;
#pragma unroll
    for (int i = 0; i < 32; i++) c += (kv[i] > T) ? 1u : 0u;
#pragma unroll
    for (int o = 32; o > 0; o >>= 1) c += __shfl_xor(c, o);
    if (lane == 0) redu[wid] = c;
    __syncthreads();
    if (t == 0) {
      unsigned v = 0;
      for (int i = 0; i < 16; i++) v += redu[i];
      s_tot = v;
      s_cnt[0] = 0;
      s_cnt[1] = 0;
    }
    __syncthreads();
  }
  const unsigned rr = CCAP - s_tot;  // # of ties (==T) to take
  const float inv = s_inv;
#pragma unroll
  for (int i = 0; i < 32; i++) {
    int n = i * 1024 + t;
    unsigned k = kv[i];
    int pos = -1;
    if (k > T) {
      pos = (int)atomicAdd(&s_cnt[0], 1u);
    } else if (k == T) {
      unsigned qq = atomicAdd(&s_cnt[1], 1u);
      if (qq < rr) pos = (int)(CCAP - rr + qq);
    }
    if (pos >= 0) {
      sel_idx[e * CCAP + pos] = n;
      sel_val[e * CCAP + pos] = expf(lv[i] - m) * inv;
    }
  }
}

// ---------------- gather selected rows: Xsel[e][c][:] = bf16(x[tok][:]) ----------------
__global__ void k_gather(const float* __restrict__ x, const int* __restrict__ sel_idx,
                         short* __restrict__ Xsel) {
  const int r = blockIdx.x * 4 + (threadIdx.x >> 6);  // e*CCAP + c
  const int lane = threadIdx.x & 63;
  const int tok = sel_idx[r];
  const float* src = x + (size_t)tok * DIM + lane * 8;
  floatx4 a = *(const floatx4*)src;
  floatx4 b = *(const floatx4*)(src + 4);
  shortx8 o;
  o[0] = f2bf(a.x); o[1] = f2bf(a.y); o[2] = f2bf(a.z); o[3] = f2bf(a.w);
  o[4] = f2bf(b.x); o[5] = f2bf(b.y); o[6] = f2bf(b.z); o[7] = f2bf(b.w);
  *(shortx8*)(Xsel + (size_t)r * DIM + lane * 8) = o;
}

// ---------------- GEMM1: H = gelu(Xsel[C,512] @ W1 + b1), bf16 out, BK=64, XOR-swizzled LDS ---
__global__ __launch_bounds__(256) void k_gemm1(
    const short* __restrict__ Xsel, const short* __restrict__ w1t,
    const float* __restrict__ b1, short* __restrict__ H, int e0) {
  __shared__ short ldsA[128 * 64];
  __shared__ short ldsB[128 * 64];
  const int zi = blockIdx.z;
  const int e = e0 + zi;
  const int c0 = blockIdx.y * 128;
  const int f0 = blockIdx.x * 128;
  const int t = threadIdx.x;
  const int lane = t & 63;
  const int w = t >> 6;
  const int wm = w & 1, wn = w >> 1;
  const int row8 = t >> 3;                 // staging row 0..31 (+i*32)
  const int su = (t & 7) ^ (row8 & 7);     // swizzled source 16B-unit

  const short* gA = Xsel + ((size_t)e * CCAP + c0 + row8) * DIM + su * 8;
  const short* gB = w1t + ((size_t)e * NF + f0 + row8) * DIM + su * 8;

  floatx4 acc[4][4];
#pragma unroll
  for (int i = 0; i < 4; i++)
#pragma unroll
    for (int j = 0; j < 4; j++) acc[i][j] = (floatx4){0.f, 0.f, 0.f, 0.f};

  const int arow = wm * 64 + (lane & 15);
  const int brow = wn * 64 + (lane & 15);
  const int lx = lane & 7, q = lane >> 4;

  for (int kk = 0; kk < DIM / 64; ++kk) {
    __syncthreads();
#pragma unroll
    for (int i = 0; i < 4; i++) {
      gll16(gA + (size_t)i * 32 * DIM, ldsA + i * 2048 + t * 8);
      gll16(gB + (size_t)i * 32 * DIM, ldsB + i * 2048 + t * 8);
    }
    gA += 64; gB += 64;
    __syncthreads();
#pragma unroll
    for (int g = 0; g < 2; g++) {
      const int pu = (((g << 2) | q) ^ lx) << 3;  // physical unit byte-offset/2
      shortx8 af[4], bf[4];
#pragma unroll
      for (int i = 0; i < 4; i++)
        af[i] = *(const shortx8*)&ldsA[(arow + i * 16) * 64 + pu];
#pragma unroll
      for (int j = 0; j < 4; j++)
        bf[j] = *(const shortx8*)&ldsB[(brow + j * 16) * 64 + pu];
#pragma unroll
      for (int i = 0; i < 4; i++)
#pragma unroll
        for (int j = 0; j < 4; j++)
          acc[i][j] = __builtin_amdgcn_mfma_f32_16x16x32_bf16(af[i], bf[j], acc[i][j], 0, 0, 0);
    }
  }

  const int colb = wn * 64 + (lane & 15);
  const int rowb = wm * 64 + ((lane >> 4) << 2);
  const float* b1p = b1 + e * NF + f0;
  short* Hp = H + (size_t)zi * CCAP * NF;
#pragma unroll
  for (int j = 0; j < 4; j++) {
    float bv = b1p[colb + j * 16];
#pragma unroll
    for (int i = 0; i < 4; i++) {
#pragma unroll
      for (int r = 0; r < 4; r++) {
        float h = acc[i][j][r] + bv;
        float gl = 0.5f * h * (1.0f + erff(h * 0.7071067811865475f));
        Hp[(size_t)(c0 + rowb + i * 16 + r) * NF + f0 + colb + j * 16] = f2bf(gl);
      }
    }
  }
}

// ---------------- GEMM2: out[tok] += val * (H @ W2 + b2), BK=64, XOR-swizzled LDS -----------
__global__ __launch_bounds__(256) void k_gemm2(
    const short* __restrict__ H, const short* __restrict__ w2t,
    const float* __restrict__ b2, const int* __restrict__ sel_idx,
    const float* __restrict__ sel_val, float* __restrict__ out, int e0) {
  __shared__ short ldsA[128 * 64];
  __shared__ short ldsB[128 * 64];
  __shared__ int tokL[128];
  __shared__ float valL[128];
  const int zi = blockIdx.z;
  const int e = e0 + zi;
  const int c0 = blockIdx.y * 128;
  const int d0 = blockIdx.x * 128;
  const int t = threadIdx.x;
  const int lane = t & 63;
  const int w = t >> 6;
  const int wm = w & 1, wn = w >> 1;
  if (t < 128) {
    tokL[t] = sel_idx[e * CCAP + c0 + t];
    valL[t] = sel_val[e * CCAP + c0 + t];
  }
  const int row8 = t >> 3;
  const int su = (t & 7) ^ (row8 & 7);

  const short* gA = H + ((size_t)zi * CCAP + c0 + row8) * NF + su * 8;
  const short* gB = w2t + ((size_t)e * DIM + d0 + row8) * NF + su * 8;

  floatx4 acc[4][4];
#pragma unroll
  for (int i = 0; i < 4; i++)
#pragma unroll
    for (int j = 0; j < 4; j++) acc[i][j] = (floatx4){0.f, 0.f, 0.f, 0.f};

  const int arow = wm * 64 + (lane & 15);
  const int brow = wn * 64 + (lane & 15);
  const int lx = lane & 7, q = lane >> 4;

  for (int kk = 0; kk < NF / 64; ++kk) {
    __syncthreads();
#pragma unroll
    for (int i = 0; i < 4; i++) {
      gll16(gA + (size_t)i * 32 * NF, ldsA + i * 2048 + t * 8);
      gll16(gB + (size_t)i * 32 * NF, ldsB + i * 2048 + t * 8);
    }
    gA += 64; gB += 64;
    __syncthreads();
#pragma unroll
    for (int g = 0; g < 2; g++) {
      const int pu = (((g << 2) | q) ^ lx) << 3;
      shortx8 af[4], bf[4];
#pragma unroll
      for (int i = 0; i < 4; i++)
        af[i] = *(const shortx8*)&ldsA[(arow + i * 16) * 64 + pu];
#pragma unroll
      for (int j = 0; j < 4; j++)
        bf[j] = *(const shortx8*)&ldsB[(brow + j * 16) * 64 + pu];
#pragma unroll
      for (int i = 0; i < 4; i++)
#pragma unroll
        for (int j = 0; j < 4; j++)
          acc[i][j] = __builtin_amdgcn_mfma_f32_16x16x32_bf16(af[i], bf[j], acc[i][j], 0, 0, 0);
    }
  }

  const int colb = wn * 64 + (lane & 15);
  const int rowb = wm * 64 + ((lane >> 4) << 2);
  const float* b2p = b2 + e * DIM + d0;
#pragma unroll
  for (int j = 0; j < 4; j++) {
    float bv = b2p[colb + j * 16];
#pragma unroll
    for (int i = 0; i < 4; i++) {
#pragma unroll
      for (int r = 0; r < 4; r++) {
        int row = rowb + i * 16 + r;
        float o = acc[i][j][r] + bv;
        atomicAdd(&out[(size_t)tokL[row] * DIM + d0 + colb + j * 16], valL[row] * o);
      }
    }
  }
}

extern "C" void kernel_launch(void* const* d_in, const int* in_sizes, int n_in,
                              void* d_out, int out_size, void* d_ws, size_t ws_size,
                              hipStream_t stream) {
  const float* x = (const float*)d_in[0];
  const float* Wr = (const float*)d_in[1];
  const float* W1 = (const float*)d_in[2];
  const float* b1 = (const float*)d_in[3];
  const float* W2 = (const float*)d_in[4];
  const float* b2 = (const float*)d_in[5];
  float* out = (float*)d_out;

  char* p = (char*)d_ws;
  size_t off = 0;
  auto carve = [&](size_t bytes) {
    void* r = p + off;
    off = (off + bytes + 255) & ~(size_t)255;
    return r;
  };
  short* w1t = (short*)carve((size_t)NE * NF * DIM * 2);
  short* w2t = (short*)carve((size_t)NE * DIM * NF * 2);
  float* logitsT = (float*)carve((size_t)NE * N_TOK * 4);
  int* selidx = (int*)carve((size_t)NE * CCAP * 4);
  float* selval = (float*)carve((size_t)NE * CCAP * 4);
  short* Xsel = (short*)carve((size_t)NE * CCAP * DIM * 2);
  const size_t hbytes = (size_t)CCAP * NF * 2;
  int g = 1;
  if (off + 8 * hbytes <= ws_size) g = 8;
  else if (off + 4 * hbytes <= ws_size) g = 4;
  else if (off + 2 * hbytes <= ws_size) g = 2;
  short* Hbuf = (short*)carve((size_t)g * hbytes);

  hipMemsetAsync(d_out, 0, (size_t)out_size * 4, stream);
  k_transpose<<<dim3(NF / 32, DIM / 32, NE), dim3(32, 8), 0, stream>>>(W1, w1t, DIM, NF);
  k_transpose<<<dim3(DIM / 32, NF / 32, NE), dim3(32, 8), 0, stream>>>(W2, w2t, NF, DIM);
  k_logits<<<2048, 256, 0, stream>>>(x, Wr, logitsT);
  k_select<<<NE, 1024, 0, stream>>>(logitsT, selidx, selval);
  k_gather<<<NE * CCAP / 4, 256, 0, stream>>>(x, selidx, Xsel);
  for (int e0 = 0; e0 < NE; e0 += g) {
    k_gemm1<<<dim3(NF / 128, CCAP / 128, g), 256, 0, stream>>>(Xsel, w1t, b1, Hbuf, e0);
    k_gemm2<<<dim3(DIM / 128, CCAP / 128, g), 256, 0, stream>>>(Hbuf, w2t, b2, selidx, selval, out, e0);
  }
}

// Round 3
// 590.578 us; speedup vs baseline: 1.1092x; 1.0627x over previous
//
#include <hip/hip_runtime.h>
#include <math.h>

#define N_TOK 32768
#define DIM 512
#define NE 8
#define NF 2048
#define CCAP 4096

typedef __attribute__((ext_vector_type(4))) float floatx4;
typedef __attribute__((ext_vector_type(8))) short shortx8;
typedef __attribute__((ext_vector_type(4))) short shortx4;

__device__ __forceinline__ short f2bf(float f) {
  union { float f; unsigned u; } v; v.f = f;
  unsigned r = v.u + 0x7FFFu + ((v.u >> 16) & 1u);
  return (short)(r >> 16);
}

__device__ __forceinline__ unsigned f2key(float f) {
  union { float f; unsigned u; } v; v.f = f;
  return (v.u & 0x80000000u) ? ~v.u : (v.u | 0x80000000u);
}

__device__ __forceinline__ void gll16(const void* g, void* l) {
  __builtin_amdgcn_global_load_lds(
      (const __attribute__((address_space(1))) void*)g,
      (__attribute__((address_space(3))) void*)l, 16, 0, 0);
}

__device__ __forceinline__ float fast_gelu(float h) {
  // 0.5h(1+tanh(0.79788456(h+0.044715h^3))), tanh via exp2
  float u = 0.7978845608f * (h + 0.044715f * h * h * h);
  float au = fabsf(u) * 2.885390082f;  // 2*log2(e)*|u|
  float z = __builtin_amdgcn_exp2f(au);
  float th = 1.0f - 2.0f * __builtin_amdgcn_rcpf(1.0f + z);
  th = copysignf(th, u);
  return 0.5f * h * (1.0f + th);
}

// ============ prep: W1/W2 transpose+convert, zero out, x->bf16, router logits ============
__global__ __launch_bounds__(256) void k_prep(
    const float* __restrict__ x, const float* __restrict__ W1,
    const float* __restrict__ W2, const float* __restrict__ Wr,
    float* __restrict__ out, short* __restrict__ xb,
    short* __restrict__ w1t, short* __restrict__ w2t,
    float* __restrict__ logitsT) {
  __shared__ float tl[64 * 68];
  const int b = blockIdx.x, t = threadIdx.x;
  if (b < 4096) {
    // 64x64 transpose tiles: fp32 [R][C] -> bf16 [C][R]
    const float* in;
    short* o;
    int R, C, c0, r0;
    if (b < 2048) {
      int e = b >> 8, tlid = b & 255;
      in = W1 + (size_t)e * DIM * NF;
      o = w1t + (size_t)e * NF * DIM;
      R = DIM; C = NF;
      c0 = (tlid & 31) * 64; r0 = (tlid >> 5) * 64;
    } else {
      int bb = b - 2048;
      int e = bb >> 8, tlid = bb & 255;
      in = W2 + (size_t)e * NF * DIM;
      o = w2t + (size_t)e * DIM * NF;
      R = NF; C = DIM;
      c0 = (tlid & 7) * 64; r0 = (tlid >> 3) * 64;
    }
    const int r = t >> 4, cq = (t & 15) * 4;
#pragma unroll
    for (int ii = 0; ii < 4; ii++) {
      floatx4 v = *(const floatx4*)&in[(size_t)(r0 + r + 16 * ii) * C + c0 + cq];
      *(floatx4*)&tl[(r + 16 * ii) * 68 + cq] = v;
    }
    __syncthreads();
    const int cc = t >> 2, rq = (t & 3) * 16;
    shortx8 o0, o1;
#pragma unroll
    for (int k = 0; k < 8; k++) o0[k] = f2bf(tl[(rq + k) * 68 + cc]);
#pragma unroll
    for (int k = 0; k < 8; k++) o1[k] = f2bf(tl[(rq + 8 + k) * 68 + cc]);
    size_t ob = (size_t)(c0 + cc) * R + r0 + rq;
    *(shortx8*)&o[ob] = o0;
    *(shortx8*)&o[ob + 8] = o1;
  } else if (b < 4608) {
    // zero out
    const int base = (b - 4096) * 8192 + t;
    floatx4 z = {0.f, 0.f, 0.f, 0.f};
#pragma unroll
    for (int i = 0; i < 32; i++) *(floatx4*)&out[(size_t)(base + i * 256) * 4] = z;
  } else if (b < 5120) {
    // x -> bf16
    const int base = (b - 4608) * 8192 + t;
#pragma unroll
    for (int i = 0; i < 32; i++) {
      floatx4 v = *(const floatx4*)&x[(size_t)(base + i * 256) * 4];
      shortx4 s;
      s.x = f2bf(v.x); s.y = f2bf(v.y); s.z = f2bf(v.z); s.w = f2bf(v.w);
      *(shortx4*)&xb[(size_t)(base + i * 256) * 4] = s;
    }
  } else {
    // router logits (fp64 accumulate), logitsT[e][n]
    const int lane = t & 63;
    const int wave = (b - 5120) * 4 + (t >> 6);
    float wr[64];
#pragma unroll
    for (int i = 0; i < 16; i++)
      *(floatx4*)&wr[i * 4] = *(const floatx4*)&Wr[lane * 64 + i * 4];
    for (int n = wave; n < N_TOK; n += 4096) {
      const float* xr = x + (size_t)n * DIM + lane * 8;
      floatx4 x0 = *(const floatx4*)xr;
      floatx4 x1 = *(const floatx4*)(xr + 4);
      float xs[8] = {x0.x, x0.y, x0.z, x0.w, x1.x, x1.y, x1.z, x1.w};
      double acc[8];
#pragma unroll
      for (int e2 = 0; e2 < 8; e2++) acc[e2] = 0.0;
#pragma unroll
      for (int j = 0; j < 8; j++) {
        double xv = (double)xs[j];
#pragma unroll
        for (int e2 = 0; e2 < 8; e2++) acc[e2] += xv * (double)wr[j * 8 + e2];
      }
#pragma unroll
      for (int e2 = 0; e2 < 8; e2++) {
#pragma unroll
        for (int off2 = 32; off2 > 0; off2 >>= 1)
          acc[e2] += __shfl_xor(acc[e2], off2);
      }
      double rv = acc[0];
#pragma unroll
      for (int e2 = 1; e2 < 8; e2++)
        if (lane == e2) rv = acc[e2];
      if (lane < 8) logitsT[(size_t)lane * N_TOK + n] = (float)rv;
    }
  }
}

// ============ exact top-C via register bisection + ballot compaction ============
__global__ __launch_bounds__(1024) void k_select(const float* __restrict__ logitsT,
                                                 int* __restrict__ sel_idx,
                                                 float* __restrict__ sel_val) {
  __shared__ float redf[16];
  __shared__ unsigned redu[16];
  __shared__ float s_max, s_inv;
  __shared__ unsigned s_tot;
  __shared__ unsigned s_cnt[2];
  const int e = blockIdx.x, t = threadIdx.x;
  const int wid = t >> 6, lane = t & 63;
  const float* lg = logitsT + (size_t)e * N_TOK;
  float lv[32];
  unsigned kv[32];
#pragma unroll
  for (int i = 0; i < 32; i++) lv[i] = lg[i * 1024 + t];
#pragma unroll
  for (int i = 0; i < 32; i++) kv[i] = f2key(lv[i]);
  float m = lv[0];
#pragma unroll
  for (int i = 1; i < 32; i++) m = fmaxf(m, lv[i]);
#pragma unroll
  for (int o = 32; o > 0; o >>= 1) m = fmaxf(m, __shfl_xor(m, o));
  if (lane == 0) redf[wid] = m;
  __syncthreads();
  if (t == 0) {
    float v = redf[0];
    for (int i = 1; i < 16; i++) v = fmaxf(v, redf[i]);
    s_max = v;
  }
  __syncthreads();
  m = s_max;
  float s = 0.f;
#pragma unroll
  for (int i = 0; i < 32; i++) s += expf(lv[i] - m);
#pragma unroll
  for (int o = 32; o > 0; o >>= 1) s += __shfl_xor(s, o);
  if (lane == 0) redf[wid] = s;
  __syncthreads();
  if (t == 0) {
    float v = 0.f;
    for (int i = 0; i < 16; i++) v += redf[i];
    s_inv = 1.0f / v;
  }
  unsigned T = 0;
  for (int bb = 31; bb >= 0; --bb) {
    unsigned cand = T | (1u << bb);
    unsigned c = 0;
#pragma unroll
    for (int i = 0; i < 32; i++) c += (kv[i] >= cand) ? 1u : 0u;
#pragma unroll
    for (int o = 32; o > 0; o >>= 1) c += __shfl_xor(c, o);
    if (lane == 0) redu[wid] = c;
    __syncthreads();
    if (t == 0) {
      unsigned v = 0;
      for (int i = 0; i < 16; i++) v += redu[i];
      s_tot = v;
    }
    __syncthreads();
    if (s_tot >= CCAP) T = cand;
  }
  {
    unsigned c = 0;
#pragma unroll
    for (int i = 0; i < 32; i++) c += (kv[i] > T) ? 1u : 0u;
#pragma unroll
    for (int o = 32; o > 0; o >>= 1) c += __shfl_xor(c, o);
    if (lane == 0) redu[wid] = c;
    __syncthreads();
    if (t == 0) {
      unsigned v = 0;
      for (int i = 0; i < 16; i++) v += redu[i];
      s_tot = v;
      s_cnt[0] = 0;
      s_cnt[1] = 0;
    }
    __syncthreads();
  }
  const unsigned rr = CCAP - s_tot;
  const float inv = s_inv;
  const unsigned long long lmask = (1ull << lane) - 1ull;
#pragma unroll
  for (int i = 0; i < 32; i++) {
    int n = i * 1024 + t;
    bool gt = kv[i] > T;
    bool eq = kv[i] == T;
    unsigned long long mg = __ballot(gt);
    unsigned long long mq = __ballot(eq);
    unsigned bg = 0, bq = 0;
    if (lane == 0) {
      if (mg) bg = atomicAdd(&s_cnt[0], (unsigned)__popcll(mg));
      if (mq) bq = atomicAdd(&s_cnt[1], (unsigned)__popcll(mq));
    }
    bg = __shfl(bg, 0);
    bq = __shfl(bq, 0);
    int pos = -1;
    if (gt) {
      pos = (int)(bg + (unsigned)__popcll(mg & lmask));
    } else if (eq) {
      unsigned qq = bq + (unsigned)__popcll(mq & lmask);
      if (qq < rr) pos = (int)(CCAP - rr + qq);
    }
    if (pos >= 0) {
      sel_idx[e * CCAP + pos] = n;
      sel_val[e * CCAP + pos] = expf(lv[i] - m) * inv;
    }
  }
}

// ============ GEMM1: H = gelu(gather(xb)[256-tile,512] @ W1 + b1) ============
// block tile 256x128, wave tile 128x64 (8x4), BK=64. A via LDS(gll16), B direct-to-reg.
__global__ __launch_bounds__(256, 2) void k_gemm1(
    const short* __restrict__ xb, const short* __restrict__ w1t,
    const float* __restrict__ b1, const int* __restrict__ sel_idx,
    short* __restrict__ H, int e0) {
  __shared__ char smem[256 * 136 * 2];  // 69632 B; staging uses first 32768 B
  short* ldsA = (short*)smem;
  const int zi = blockIdx.z;
  const int e = e0 + zi;
  const int c0 = blockIdx.y * 256;
  const int f0 = blockIdx.x * 128;
  const int t = threadIdx.x;
  const int lane = t & 63;
  const int w = t >> 6;
  const int wm = w & 1, wn = w >> 1;
  const int row8 = t >> 3;
  const int su = (t & 7) ^ (row8 & 7);

  const short* gAp[8];
#pragma unroll
  for (int i = 0; i < 8; i++) {
    int tok = sel_idx[e * CCAP + c0 + row8 + i * 32];
    gAp[i] = xb + (size_t)tok * DIM + su * 8;
  }
  const short* gB = w1t + ((size_t)(e * NF + f0 + wn * 64 + (lane & 15))) * DIM + (lane >> 4) * 8;

  floatx4 acc[8][4];
#pragma unroll
  for (int i = 0; i < 8; i++)
#pragma unroll
    for (int j = 0; j < 4; j++) acc[i][j] = (floatx4){0.f, 0.f, 0.f, 0.f};

  const int arow = wm * 128 + (lane & 15);
  const int lx = lane & 7, q = lane >> 4;

  for (int kk = 0; kk < DIM / 64; ++kk) {
    __syncthreads();
#pragma unroll
    for (int i = 0; i < 8; i++) gll16(gAp[i], ldsA + i * 2048 + t * 8);
#pragma unroll
    for (int i = 0; i < 8; i++) gAp[i] += 64;
    __syncthreads();
#pragma unroll
    for (int g = 0; g < 2; g++) {
      const int pu = ((((g << 2) | q)) ^ lx) << 3;
      shortx8 bf[4];
#pragma unroll
      for (int j = 0; j < 4; j++)
        bf[j] = *(const shortx8*)(gB + (size_t)j * 16 * DIM + kk * 64 + g * 32);
      shortx8 af[8];
#pragma unroll
      for (int i = 0; i < 8; i++)
        af[i] = *(const shortx8*)&ldsA[(arow + i * 16) * 64 + pu];
#pragma unroll
      for (int i = 0; i < 8; i++)
#pragma unroll
        for (int j = 0; j < 4; j++)
          acc[i][j] = __builtin_amdgcn_mfma_f32_16x16x32_bf16(af[i], bf[j], acc[i][j], 0, 0, 0);
    }
  }

  // epilogue: bias+gelu -> LDS restage (stride 136) -> coalesced stores
  __syncthreads();
  short* ep = (short*)smem;
  const int colL = wn * 64 + (lane & 15);
  const int rowL = wm * 128 + ((lane >> 4) << 2);
#pragma unroll
  for (int j = 0; j < 4; j++) {
    float bv = b1[e * NF + f0 + colL + j * 16];
#pragma unroll
    for (int i = 0; i < 8; i++) {
#pragma unroll
      for (int r = 0; r < 4; r++) {
        float h = acc[i][j][r] + bv;
        ep[(rowL + i * 16 + r) * 136 + colL + j * 16] = f2bf(fast_gelu(h));
      }
    }
  }
  __syncthreads();
  short* Hp = H + (size_t)zi * CCAP * NF;
  const int chunk = t & 15;  // 16B chunk within row
#pragma unroll
  for (int it = 0; it < 16; it++) {
    int r = (t >> 4) + 16 * it;
    shortx8 v = *(const shortx8*)&ep[r * 136 + chunk * 8];
    *(shortx8*)&Hp[(size_t)(c0 + r) * NF + f0 + chunk * 8] = v;
  }
}

// ============ GEMM2: out[tok] += val * (H @ W2 + b2) ============
// block tile 256x128, wave tile 128x64 (8x4), BK=64. A via LDS(gll16), B direct-to-reg.
__global__ __launch_bounds__(256, 2) void k_gemm2(
    const short* __restrict__ H, const short* __restrict__ w2t,
    const float* __restrict__ b2, const int* __restrict__ sel_idx,
    const float* __restrict__ sel_val, float* __restrict__ out, int e0) {
  __shared__ short ldsA[256 * 64];  // 32 KB
  __shared__ int tokL[256];
  __shared__ float valL[256];
  const int zi = blockIdx.z;
  const int e = e0 + zi;
  const int c0 = blockIdx.y * 256;
  const int d0 = blockIdx.x * 128;
  const int t = threadIdx.x;
  const int lane = t & 63;
  const int w = t >> 6;
  const int wm = w & 1, wn = w >> 1;
  tokL[t] = sel_idx[e * CCAP + c0 + t];
  valL[t] = sel_val[e * CCAP + c0 + t];
  const int row8 = t >> 3;
  const int su = (t & 7) ^ (row8 & 7);

  const short* gA = H + ((size_t)zi * CCAP + c0 + row8) * NF + su * 8;
  const short* gB = w2t + ((size_t)(e * DIM + d0 + wn * 64 + (lane & 15))) * NF + (lane >> 4) * 8;

  floatx4 acc[8][4];
#pragma unroll
  for (int i = 0; i < 8; i++)
#pragma unroll
    for (int j = 0; j < 4; j++) acc[i][j] = (floatx4){0.f, 0.f, 0.f, 0.f};

  const int arow = wm * 128 + (lane & 15);
  const int lx = lane & 7, q = lane >> 4;

  for (int kk = 0; kk < NF / 64; ++kk) {
    __syncthreads();
#pragma unroll
    for (int i = 0; i < 8; i++)
      gll16(gA + (size_t)i * 32 * NF + kk * 64, ldsA + i * 2048 + t * 8);
    __syncthreads();
#pragma unroll
    for (int g = 0; g < 2; g++) {
      const int pu = ((((g << 2) | q)) ^ lx) << 3;
      shortx8 bf[4];
#pragma unroll
      for (int j = 0; j < 4; j++)
        bf[j] = *(const shortx8*)(gB + (size_t)j * 16 * NF + kk * 64 + g * 32);
      shortx8 af[8];
#pragma unroll
      for (int i = 0; i < 8; i++)
        af[i] = *(const shortx8*)&ldsA[(arow + i * 16) * 64 + pu];
#pragma unroll
      for (int i = 0; i < 8; i++)
#pragma unroll
        for (int j = 0; j < 4; j++)
          acc[i][j] = __builtin_amdgcn_mfma_f32_16x16x32_bf16(af[i], bf[j], acc[i][j], 0, 0, 0);
    }
  }

  const int colL = wn * 64 + (lane & 15);
  const int rowL = wm * 128 + ((lane >> 4) << 2);
#pragma unroll
  for (int j = 0; j < 4; j++) {
    float bv = b2[e * DIM + d0 + colL + j * 16];
#pragma unroll
    for (int i = 0; i < 8; i++) {
#pragma unroll
      for (int r = 0; r < 4; r++) {
        int row = rowL + i * 16 + r;
        float o = acc[i][j][r] + bv;
        atomicAdd(&out[(size_t)tokL[row] * DIM + d0 + colL + j * 16], valL[row] * o);
      }
    }
  }
}

extern "C" void kernel_launch(void* const* d_in, const int* in_sizes, int n_in,
                              void* d_out, int out_size, void* d_ws, size_t ws_size,
                              hipStream_t stream) {
  const float* x = (const float*)d_in[0];
  const float* Wr = (const float*)d_in[1];
  const float* W1 = (const float*)d_in[2];
  const float* b1 = (const float*)d_in[3];
  const float* W2 = (const float*)d_in[4];
  const float* b2 = (const float*)d_in[5];
  float* out = (float*)d_out;

  char* p = (char*)d_ws;
  size_t off = 0;
  auto carve = [&](size_t bytes) {
    void* r = p + off;
    off = (off + bytes + 255) & ~(size_t)255;
    return r;
  };
  short* xb = (short*)carve((size_t)N_TOK * DIM * 2);
  short* w1t = (short*)carve((size_t)NE * NF * DIM * 2);
  short* w2t = (short*)carve((size_t)NE * DIM * NF * 2);
  float* logitsT = (float*)carve((size_t)NE * N_TOK * 4);
  int* selidx = (int*)carve((size_t)NE * CCAP * 4);
  float* selval = (float*)carve((size_t)NE * CCAP * 4);
  const size_t hbytes = (size_t)CCAP * NF * 2;
  int g = 1;
  if (off + 8 * hbytes <= ws_size) g = 8;
  else if (off + 4 * hbytes <= ws_size) g = 4;
  else if (off + 2 * hbytes <= ws_size) g = 2;
  short* Hbuf = (short*)carve((size_t)g * hbytes);

  k_prep<<<6144, 256, 0, stream>>>(x, W1, W2, Wr, out, xb, w1t, w2t, logitsT);
  k_select<<<NE, 1024, 0, stream>>>(logitsT, selidx, selval);
  for (int e0 = 0; e0 < NE; e0 += g) {
    k_gemm1<<<dim3(NF / 128, CCAP / 256, g), 256, 0, stream>>>(xb, w1t, b1, selidx, Hbuf, e0);
    k_gemm2<<<dim3(DIM / 128, CCAP / 256, g), 256, 0, stream>>>(Hbuf, w2t, b2, selidx, selval, out, e0);
  }
}